// Round 15
// baseline (235.898 us; speedup 1.0000x reference)
//
#include <hip/hip_runtime.h>
#include <hip/hip_bf16.h>
#include <math.h>

#define DF 128
#define HID 256
#define NG 256
#define CSR_CAP 768

typedef __attribute__((ext_vector_type(8))) short s8v;    // 8 bf16 (4 VGPR)
typedef __attribute__((ext_vector_type(4))) float f32x4;  // MFMA acc
typedef __attribute__((ext_vector_type(2))) float f32x2;

__device__ __forceinline__ unsigned pack2bf(float lo, float hi){
  unsigned a = __bfloat16_as_ushort(__float2bfloat16(lo));
  unsigned b = __bfloat16_as_ushort(__float2bfloat16(hi));
  return a | (b<<16);
}

// =============== k_pre0: emb table f32->fp8 (streamed) + hists + weight prep ===============
__global__ __launch_bounds__(256)
void k_pre0(const float* __restrict__ emb, unsigned* __restrict__ emb_f8, int nvoc,
            const int* __restrict__ dst, int* __restrict__ gb,
            const int* __restrict__ gid, float* __restrict__ gcnt,
            const float* __restrict__ ws0, const float* __restrict__ wn0,
            const float* __restrict__ ws1, const float* __restrict__ wn1,
            unsigned short* __restrict__ wt,
            int N, int E, int NC){
  __shared__ int hist[256];
  const int b = blockIdx.x, t = threadIdx.x;
  if (b < NC){
    int idx = b*256 + t;                 // 8-elem chunk (uint2 of fp8)
    int total = nvoc*(DF/8);
    if (idx<total){
      const float4* e4 = (const float4*)emb;
      float4 v0 = e4[(size_t)idx*2], v1 = e4[(size_t)idx*2+1];
      unsigned w0 = __builtin_amdgcn_cvt_pk_fp8_f32(v0.x, v0.y, 0, false);
      w0 = __builtin_amdgcn_cvt_pk_fp8_f32(v0.z, v0.w, w0, true);
      unsigned w1 = __builtin_amdgcn_cvt_pk_fp8_f32(v1.x, v1.y, 0, false);
      w1 = __builtin_amdgcn_cvt_pk_fp8_f32(v1.z, v1.w, w1, true);
      ((uint2*)emb_f8)[idx] = make_uint2(w0,w1);
    }
  } else if (b < NC+256){
    int bb = b - NC;
    hist[t]=0; __syncthreads();
    for (int i = bb*256+t; i < E; i += 256*256)
      atomicAdd(&hist[dst[i]>>9], 1);
    __syncthreads();
    if (hist[t]) atomicAdd(&gb[t], hist[t]);
  } else if (b < NC+512){
    int bb = b - (NC+256);
    hist[t]=0; __syncthreads();
    for (int i = bb*256+t; i < N; i += 256*256)
      atomicAdd(&hist[gid[i]], 1);
    __syncthreads();
    if (hist[t]) atomicAdd(&gcnt[t], (float)hist[t]);
  } else {
    int bb = b - (NC+512);
    int n = bb & 127;
    int layer = bb >> 7;
    const float* ws = layer? ws1 : ws0;
    const float* wn = layer? wn1 : wn0;
    float v = (t<128)? ws[t*DF+n] : wn[(t-128)*DF+n];
    wt[((size_t)layer*DF + n)*256 + t] = __bfloat16_as_ushort(__float2bfloat16(v));
  }
}

// =============== k_pre1: node gather from fp8 table (L2-resident 3.84MB) ===============
__global__ __launch_bounds__(256)
void k_pre1(const int* __restrict__ feat, const unsigned* __restrict__ emb_f8,
            unsigned* __restrict__ h_f8, int N){
  int idx = blockIdx.x*256 + threadIdx.x;   // uint4 chunk (16 fp8)
  int total = N*8;
  if (idx<total){
    int i = idx>>3, c = idx&7;
    ((uint4*)h_f8)[idx] = ((const uint4*)emb_f8)[(size_t)feat[i]*8 + c];
  }
}

// =============== binned CSR build (packed pairs: src<<9 | local_dst) ===============
// 2048 blocks: 8 blocks/CU restores TLP (R14 post-mortem: 256-block binning
// was 1 block/CU -> 9.8% occupancy -> ~55us hidden tail).
__global__ __launch_bounds__(256)
void k_bplace(const int* __restrict__ src, const int* __restrict__ dst,
              const int* __restrict__ gb, int* __restrict__ bcur,
              unsigned* __restrict__ pairs, int E){
  __shared__ int sgb[256];
  __shared__ int hist[256];
  __shared__ int base[256];
  __shared__ int cur[256];
  const int t = threadIdx.x;
  const int CH = (E + gridDim.x - 1)/gridDim.x;
  const int s = blockIdx.x*CH;
  int e = s+CH; if (e>E) e=E;
  if (s>=E) return;
  int v = gb[t];
  sgb[t]=v;
  hist[t]=0;
  __syncthreads();
  for (int o=1;o<256;o<<=1){
    int x = (t>=o)? sgb[t-o] : 0;
    __syncthreads();
    sgb[t]+=x;
    __syncthreads();
  }
  int bstart = sgb[t]-v;   // exclusive prefix = bucket t start
  for (int i=s+t; i<e; i+=256) atomicAdd(&hist[dst[i]>>9],1);
  __syncthreads();
  if (hist[t]){ base[t] = bstart + atomicAdd(&bcur[t],hist[t]); }
  cur[t]=0;
  __syncthreads();
  for (int i=s+t; i<e; i+=256){
    int d = dst[i];
    int bk = d>>9;
    int r = atomicAdd(&cur[bk],1);
    pairs[base[bk]+r] = ((unsigned)src[i]<<9) | (unsigned)(d & 511);
  }
}

__global__ __launch_bounds__(256)
void k_bcsr(const unsigned* __restrict__ pairs, const int* __restrict__ gb,
            int* __restrict__ offs, int* __restrict__ csr, int N, int E){
  __shared__ int sgb[256];
  __shared__ int ncnt[512];
  __shared__ int noff[512];
  __shared__ int sh[256];
  const int t = threadIdx.x;
  const int b = blockIdx.x;
  const int nb0 = b<<9;
  int v = gb[t];
  sgb[t]=v;
  ncnt[t]=0; ncnt[t+256]=0;
  __syncthreads();
  for (int o=1;o<256;o<<=1){
    int x = (t>=o)? sgb[t-o] : 0;
    __syncthreads();
    sgb[t]+=x;
    __syncthreads();
  }
  const int s = sgb[b]-gb[b];   // bucket b start
  const int e = sgb[b];         // bucket b end
  for (int i=s+t; i<e; i+=256) atomicAdd(&ncnt[pairs[i] & 511u], 1);
  __syncthreads();
  int v0 = ncnt[2*t], v1 = ncnt[2*t+1];
  int vv = v0+v1;
  sh[t]=vv; __syncthreads();
  for (int o=1;o<256;o<<=1){
    int x=(t>=o)?sh[t-o]:0;
    __syncthreads();
    sh[t]+=x;
    __syncthreads();
  }
  int ex = sh[t]-vv;
  noff[2*t]=ex; noff[2*t+1]=ex+v0;
  __syncthreads();
  {
    int n0 = nb0 + t;
    if (n0 < N) offs[n0] = s + noff[t];
    int n1 = nb0 + t + 256;
    if (n1 < N) offs[n1] = s + noff[t+256];
    if (b == gridDim.x-1 && t==0) offs[N] = E;
  }
  ncnt[t]=0; ncnt[t+256]=0;
  __syncthreads();
  for (int i=s+t; i<e; i+=256){
    unsigned p = pairs[i];
    int d = p & 511u;
    int r = atomicAdd(&ncnt[d],1);
    csr[s + noff[d] + r] = (int)(p >> 9);
  }
}

// ---------------- fused SAGE layer: fp8-only h, LDS-staged csr, MFMA GEMM ----------------
// CSR_CAP=768 (block slice mean 512, sigma~23 -> +11sigma never exceeds;
// uniform global fallback kept). LDS ~19.8KB -> 8 blocks/CU.
// MODE 0: write h_out fp8.  MODE 1: fused per-graph pool.
template<int MODE>
__global__ __launch_bounds__(256,8)
void k_sage(const unsigned char* __restrict__ h_in_f8,
            const int* __restrict__ offs, const int* __restrict__ csr,
            const unsigned short* __restrict__ wt,
            const float* __restrict__ bias,
            unsigned char* __restrict__ h_out_f8,
            const int* __restrict__ gid, float* __restrict__ gsum, int N){
  __shared__ __align__(16) unsigned short s_ab[32*256];   // 16KB
  __shared__ int s_csr[CSR_CAP];
  __shared__ int s_gid[32];
  __shared__ float s_tmp[DF];
  const int t = threadIdx.x;
  const int node0 = blockIdx.x*32;
  const uint4* f8r = (const uint4*)h_in_f8;   // 8 uint4 per fp8 row

  if (MODE==1 && t<32) s_gid[t] = (node0+t<N)? gid[node0+t] : -1;

  // ---- stage block csr slice (contiguous, coalesced)
  const int eBase = offs[node0];
  const int eTop  = offs[min(node0+32, N)];
  const int ecount = eTop - eBase;
  const bool useLds = (ecount <= CSR_CAP);
  if (useLds){
    for (int i=t; i<ecount; i+=256) s_csr[i] = csr[eBase+i];
  }

  const int nn = t>>3, c = t&7;
  const int sw = (nn&7)<<4;

  // ---- self row chunk: fp8 load -> bf16 unpack -> A-tile cols 0..127, swizzled
  {
    int node = node0+nn;
    uint4 q = make_uint4(0,0,0,0);
    if (node<N) q = f8r[(size_t)node*8 + c];
    f32x2 u; unsigned pk[8];
    u=__builtin_amdgcn_cvt_pk_f32_fp8(q.x,false); pk[0]=pack2bf(u[0],u[1]);
    u=__builtin_amdgcn_cvt_pk_f32_fp8(q.x,true ); pk[1]=pack2bf(u[0],u[1]);
    u=__builtin_amdgcn_cvt_pk_f32_fp8(q.y,false); pk[2]=pack2bf(u[0],u[1]);
    u=__builtin_amdgcn_cvt_pk_f32_fp8(q.y,true ); pk[3]=pack2bf(u[0],u[1]);
    u=__builtin_amdgcn_cvt_pk_f32_fp8(q.z,false); pk[4]=pack2bf(u[0],u[1]);
    u=__builtin_amdgcn_cvt_pk_f32_fp8(q.z,true ); pk[5]=pack2bf(u[0],u[1]);
    u=__builtin_amdgcn_cvt_pk_f32_fp8(q.w,false); pk[6]=pack2bf(u[0],u[1]);
    u=__builtin_amdgcn_cvt_pk_f32_fp8(q.w,true ); pk[7]=pack2bf(u[0],u[1]);
    int byte0 = nn*512 + c*32;
    *(uint4*)((char*)s_ab + ((byte0   )^sw)) = make_uint4(pk[0],pk[1],pk[2],pk[3]);
    *(uint4*)((char*)s_ab + ((byte0+16)^sw)) = make_uint4(pk[4],pk[5],pk[6],pk[7]);
  }
  __syncthreads();   // s_csr ready

  // ---- neighbor mean from fp8 rows: idx from LDS, 2-edge unroll
  {
    const int node = node0+nn;
    float a[16];
    #pragma unroll
    for (int j=0;j<16;j++) a[j]=0.f;
    if (node<N){
      int e0=offs[node], e1=offs[node+1];
      int deg = e1-e0;
      if (deg>0){
        #define ACC16(q) { \
          f32x2 u; \
          u=__builtin_amdgcn_cvt_pk_f32_fp8((q).x,false); a[0]+=u[0]; a[1]+=u[1]; \
          u=__builtin_amdgcn_cvt_pk_f32_fp8((q).x,true ); a[2]+=u[0]; a[3]+=u[1]; \
          u=__builtin_amdgcn_cvt_pk_f32_fp8((q).y,false); a[4]+=u[0]; a[5]+=u[1]; \
          u=__builtin_amdgcn_cvt_pk_f32_fp8((q).y,true ); a[6]+=u[0]; a[7]+=u[1]; \
          u=__builtin_amdgcn_cvt_pk_f32_fp8((q).z,false); a[8]+=u[0]; a[9]+=u[1]; \
          u=__builtin_amdgcn_cvt_pk_f32_fp8((q).z,true ); a[10]+=u[0]; a[11]+=u[1]; \
          u=__builtin_amdgcn_cvt_pk_f32_fp8((q).w,false); a[12]+=u[0]; a[13]+=u[1]; \
          u=__builtin_amdgcn_cvt_pk_f32_fp8((q).w,true ); a[14]+=u[0]; a[15]+=u[1]; }
        if (useLds){
          int le = e0 - eBase, le1 = e1 - eBase;
          for (; le+2<=le1; le+=2){
            int s0 = s_csr[le], s1 = s_csr[le+1];
            uint4 q0 = f8r[(size_t)s0*8 + c];
            uint4 q1 = f8r[(size_t)s1*8 + c];
            ACC16(q0); ACC16(q1);
          }
          if (le<le1){
            uint4 q0 = f8r[(size_t)s_csr[le]*8 + c];
            ACC16(q0);
          }
        } else {
          int e = e0;
          for (; e+2<=e1; e+=2){
            int s0 = csr[e], s1 = csr[e+1];
            uint4 q0 = f8r[(size_t)s0*8 + c];
            uint4 q1 = f8r[(size_t)s1*8 + c];
            ACC16(q0); ACC16(q1);
          }
          if (e<e1){
            uint4 q0 = f8r[(size_t)csr[e]*8 + c];
            ACC16(q0);
          }
        }
        #undef ACC16
        float inv = 1.0f/(float)deg;
        #pragma unroll
        for (int j=0;j<16;j++) a[j]*=inv;
      }
    }
    unsigned pk[8];
    #pragma unroll
    for (int j=0;j<8;j++) pk[j] = pack2bf(a[2*j],a[2*j+1]);
    int byte0 = nn*512 + 256 + c*32;
    *(uint4*)((char*)s_ab + ((byte0   )^sw)) = make_uint4(pk[0],pk[1],pk[2],pk[3]);
    *(uint4*)((char*)s_ab + ((byte0+16)^sw)) = make_uint4(pk[4],pk[5],pk[6],pk[7]);
  }

  const int wv = t>>6;
  const int lr = t&15;
  const int kg = (t&63)>>4;
  __syncthreads();

  // ---- MFMA main loop, B loaded per K-half from global (L2-resident)
  f32x4 acc00={0,0,0,0}, acc01={0,0,0,0}, acc10={0,0,0,0}, acc11={0,0,0,0};
  const s8v* wt8 = (const s8v*)wt;
  #pragma unroll
  for (int kh=0; kh<2; kh++){
    s8v bfrag[2][4];
    #pragma unroll
    for (int ks=0; ks<4; ks++){
      int kb = (kh*4+ks)*4 + kg;
      bfrag[0][ks] = wt8[(size_t)(wv*32     + lr)*32 + kb];
      bfrag[1][ks] = wt8[(size_t)(wv*32 + 16+ lr)*32 + kb];
    }
    #pragma unroll
    for (int ks=0; ks<4; ks++){
      int cb = (kh*4+ks)*64 + kg*16;
      int r0 = lr, r1 = 16+lr;
      s8v a0 = *(const s8v*)((const char*)s_ab + ((r0*512+cb) ^ ((r0&7)<<4)));
      s8v a1 = *(const s8v*)((const char*)s_ab + ((r1*512+cb) ^ ((r1&7)<<4)));
      acc00 = __builtin_amdgcn_mfma_f32_16x16x32_bf16(a0, bfrag[0][ks], acc00, 0,0,0);
      acc01 = __builtin_amdgcn_mfma_f32_16x16x32_bf16(a0, bfrag[1][ks], acc01, 0,0,0);
      acc10 = __builtin_amdgcn_mfma_f32_16x16x32_bf16(a1, bfrag[0][ks], acc10, 0,0,0);
      acc11 = __builtin_amdgcn_mfma_f32_16x16x32_bf16(a1, bfrag[1][ks], acc11, 0,0,0);
    }
  }
  __syncthreads();

  // ---- epilogue: acc -> LDS f32 [32][128]
  float* cbuf = (float*)s_ab;
  #pragma unroll
  for (int r=0;r<4;r++){
    int row0 = kg*4 + r;
    cbuf[(row0   )*DF + wv*32      + lr] = acc00[r];
    cbuf[(row0   )*DF + wv*32 + 16 + lr] = acc01[r];
    cbuf[(row0+16)*DF + wv*32      + lr] = acc10[r];
    cbuf[(row0+16)*DF + wv*32 + 16 + lr] = acc11[r];
  }
  __syncthreads();

  if (MODE==0){
    int row = t>>3, c0 = (t&7)*16;
    int node = node0+row;
    if (node<N){
      float x[16];
      #pragma unroll
      for (int j=0;j<16;j++) x[j] = fmaxf(cbuf[row*DF + c0 + j] + bias[c0+j], 0.f);
      unsigned f0 = __builtin_amdgcn_cvt_pk_fp8_f32(x[0], x[1], 0, false);
      f0 = __builtin_amdgcn_cvt_pk_fp8_f32(x[2], x[3], f0, true);
      unsigned f1 = __builtin_amdgcn_cvt_pk_fp8_f32(x[4], x[5], 0, false);
      f1 = __builtin_amdgcn_cvt_pk_fp8_f32(x[6], x[7], f1, true);
      unsigned f2 = __builtin_amdgcn_cvt_pk_fp8_f32(x[8], x[9], 0, false);
      f2 = __builtin_amdgcn_cvt_pk_fp8_f32(x[10], x[11], f2, true);
      unsigned f3 = __builtin_amdgcn_cvt_pk_fp8_f32(x[12], x[13], 0, false);
      f3 = __builtin_amdgcn_cvt_pk_fp8_f32(x[14], x[15], f3, true);
      *(uint4*)&h_out_f8[(size_t)node*DF + c0] = make_uint4(f0,f1,f2,f3);
    }
  } else {
    // fused pool: segment loop over sorted gid runs; one atomic per (segment,d)
    const int d = t&127, rh = t>>7;
    const float bd = bias[d];
    int segStart = 0;
    while (segStart < 32 && s_gid[segStart] >= 0){
      int g = s_gid[segStart];
      int segEnd = segStart+1;
      while (segEnd < 32 && s_gid[segEnd] == g) segEnd++;
      float p = 0.f;
      for (int r = segStart+rh; r < segEnd; r += 2)
        p += fmaxf(cbuf[r*DF + d] + bd, 0.f);
      if (rh==1) s_tmp[d] = p;
      __syncthreads();
      if (rh==0) atomicAdd(&gsum[g*DF+d], p + s_tmp[d]);
      __syncthreads();
      segStart = segEnd;
    }
  }
}

// ---------------- fused MLP head ----------------
__global__ __launch_bounds__(256)
void k_head(const float* __restrict__ gsum, const float* __restrict__ gcnt,
            const float* __restrict__ e1w, const float* __restrict__ e1b,
            const float* __restrict__ e2w, const float* __restrict__ e2b,
            const float* __restrict__ e3w, const float* __restrict__ e3b,
            const float* __restrict__ e4w, const float* __restrict__ e4b,
            const float* __restrict__ pw,  const float* __restrict__ pb,
            float* __restrict__ out, float* __restrict__ hidden){
  __shared__ float hg[DF];
  __shared__ float bufA[HID];
  __shared__ float bufB[HID];
  __shared__ float r0[HID], r1[HID];
  const int g = blockIdx.x, t = threadIdx.x;
  if (t<DF) hg[t] = gsum[g*DF+t] / fmaxf(gcnt[g],1.0f);
  __syncthreads();

  float acc = e1b[t];
  for (int k=0;k<DF;++k) acc += hg[k]*e1w[k*HID+t];
  float h1 = fmaxf(acc,0.f);
  hidden[g*HID+t] = h1;
  bufA[t] = h1;
  __syncthreads();

  acc = e2b[t];
  for (int k=0;k<HID;++k) acc += bufA[k]*e2w[k*HID+t];
  bufB[t] = fmaxf(acc,0.f);
  __syncthreads();

  acc = e3b[t];
  for (int k=0;k<HID;++k) acc += bufB[k]*e3w[k*HID+t];
  bufA[t] = fmaxf(acc,0.f);
  __syncthreads();

  acc = e4b[t];
  for (int k=0;k<HID;++k) acc += bufA[k]*e4w[k*HID+t];
  float h4 = fmaxf(acc,0.f);

  r0[t] = h4*pw[t*2+0];
  r1[t] = h4*pw[t*2+1];
  __syncthreads();
  for (int o=128;o>0;o>>=1){
    if (t<o){ r0[t]+=r0[t+o]; r1[t]+=r1[t+o]; }
    __syncthreads();
  }
  if (t==0){
    float y0 = r0[0]+pb[0], y1 = r1[0]+pb[1];
    float m = fmaxf(y0,y1);
    float l = m + logf(expf(y0-m)+expf(y1-m));
    out[g*2+0]=y0-l;
    out[g*2+1]=y1-l;
  }
}

extern "C" void kernel_launch(void* const* d_in, const int* in_sizes, int n_in,
                              void* d_out, int out_size, void* d_ws, size_t ws_size,
                              hipStream_t stream){
  const int* feat = (const int*)d_in[0];
  const int* src  = (const int*)d_in[1];
  const int* dst  = (const int*)d_in[2];
  const int* gid  = (const int*)d_in[3];
  const float* emb = (const float*)d_in[4];
  const float* ws0 = (const float*)d_in[5];
  const float* wn0 = (const float*)d_in[6];
  const float* b0  = (const float*)d_in[7];
  const float* ws1 = (const float*)d_in[8];
  const float* wn1 = (const float*)d_in[9];
  const float* b1  = (const float*)d_in[10];
  const float* e1w = (const float*)d_in[11];
  const float* e1b = (const float*)d_in[12];
  const float* e2w = (const float*)d_in[13];
  const float* e2b = (const float*)d_in[14];
  const float* e3w = (const float*)d_in[15];
  const float* e3b = (const float*)d_in[16];
  const float* e4w = (const float*)d_in[17];
  const float* e4b = (const float*)d_in[18];
  const float* pw  = (const float*)d_in[19];
  const float* pb  = (const float*)d_in[20];
  const int N = in_sizes[0];
  const int E = in_sizes[1];
  const int nvoc = in_sizes[4] / DF;

  char* basep = (char*)d_ws;
  size_t off=0;
  auto alloc=[&](size_t bytes)->void*{
    void* p = basep+off; off=(off+bytes+255)&~(size_t)255; return p;
  };
  unsigned char*  hA_f8 = (unsigned char*) alloc((size_t)N*DF);
  unsigned char*  hB_f8 = (unsigned char*) alloc((size_t)N*DF);
  unsigned char*  emb_f8= (unsigned char*) alloc((size_t)nvoc*DF);
  int*   offs  = (int*)  alloc((size_t)(N+1)*4);
  int*   csr   = (int*)  alloc((size_t)E*4);
  int*   gb    = (int*)  alloc(1024);
  int*   bcur  = (int*)  alloc(1024);
  unsigned short* wtb = (unsigned short*)alloc((size_t)2*DF*256*2);
  float* gsum  = (float*)alloc((size_t)NG*DF*4);
  float* gcnt  = (float*)alloc((size_t)NG*4);
  unsigned* pairs = (unsigned*)alloc((size_t)E*4);
  float* out    = (float*)d_out;
  float* hidden = out + NG*2;

  hipMemsetAsync(gb, 0, 1024, stream);
  hipMemsetAsync(bcur, 0, 1024, stream);
  hipMemsetAsync(gsum, 0, (size_t)NG*DF*4, stream);
  hipMemsetAsync(gcnt, 0, (size_t)NG*4, stream);

  const int NBK = (N+511)>>9;
  const int NC = (nvoc*(DF/8) + 255)/256;   // emb-convert blocks
  k_pre0<<<NC+768,256,0,stream>>>(emb,(unsigned*)emb_f8,nvoc,
                                  dst,gb,gid,gcnt,
                                  ws0,wn0,ws1,wn1,wtb,N,E,NC);
  k_pre1<<<(N*8+255)/256,256,0,stream>>>(feat,(const unsigned*)emb_f8,
                                         (unsigned*)hA_f8,N);
  k_bplace<<<2048,256,0,stream>>>(src,dst,gb,bcur,pairs,E);
  k_bcsr<<<NBK,256,0,stream>>>(pairs,gb,offs,csr,N,E);

  k_sage<0><<<(N+31)/32,256,0,stream>>>(hA_f8,offs,csr,wtb,        b0,
                                        hB_f8,nullptr,nullptr,N);
  k_sage<1><<<(N+31)/32,256,0,stream>>>(hB_f8,offs,csr,wtb+DF*256, b1,
                                        nullptr,gid,gsum,N);

  k_head<<<NG,HID,0,stream>>>(gsum,gcnt,e1w,e1b,e2w,e2b,e3w,e3b,e4w,e4b,
                              pw,pb,out,hidden);
}

// Round 16
// 224.631 us; speedup vs baseline: 1.0502x; 1.0502x over previous
//
#include <hip/hip_runtime.h>
#include <hip/hip_bf16.h>
#include <math.h>

#define DF 128
#define HID 256
#define NG 256
#define CSR_CAP 768
#define BPM 40          // blocks per megabucket in place2

typedef __attribute__((ext_vector_type(8))) short s8v;    // 8 bf16 (4 VGPR)
typedef __attribute__((ext_vector_type(4))) float f32x4;  // MFMA acc
typedef __attribute__((ext_vector_type(2))) float f32x2;

__device__ __forceinline__ unsigned pack2bf(float lo, float hi){
  unsigned a = __bfloat16_as_ushort(__float2bfloat16(lo));
  unsigned b = __bfloat16_as_ushort(__float2bfloat16(hi));
  return a | (b<<16);
}

// =============== k_pre0: emb table f32->fp8 (streamed) + hists + weight prep ===============
__global__ __launch_bounds__(256)
void k_pre0(const float* __restrict__ emb, unsigned* __restrict__ emb_f8, int nvoc,
            const int* __restrict__ dst, int* __restrict__ gb,
            const int* __restrict__ gid, float* __restrict__ gcnt,
            const float* __restrict__ ws0, const float* __restrict__ wn0,
            const float* __restrict__ ws1, const float* __restrict__ wn1,
            unsigned short* __restrict__ wt,
            int N, int E, int NC){
  __shared__ int hist[256];
  const int b = blockIdx.x, t = threadIdx.x;
  if (b < NC){
    int idx = b*256 + t;                 // 8-elem chunk (uint2 of fp8)
    int total = nvoc*(DF/8);
    if (idx<total){
      const float4* e4 = (const float4*)emb;
      float4 v0 = e4[(size_t)idx*2], v1 = e4[(size_t)idx*2+1];
      unsigned w0 = __builtin_amdgcn_cvt_pk_fp8_f32(v0.x, v0.y, 0, false);
      w0 = __builtin_amdgcn_cvt_pk_fp8_f32(v0.z, v0.w, w0, true);
      unsigned w1 = __builtin_amdgcn_cvt_pk_fp8_f32(v1.x, v1.y, 0, false);
      w1 = __builtin_amdgcn_cvt_pk_fp8_f32(v1.z, v1.w, w1, true);
      ((uint2*)emb_f8)[idx] = make_uint2(w0,w1);
    }
  } else if (b < NC+256){
    int bb = b - NC;
    hist[t]=0; __syncthreads();
    for (int i = bb*256+t; i < E; i += 256*256)
      atomicAdd(&hist[dst[i]>>9], 1);
    __syncthreads();
    if (hist[t]) atomicAdd(&gb[t], hist[t]);
  } else if (b < NC+512){
    int bb = b - (NC+256);
    hist[t]=0; __syncthreads();
    for (int i = bb*256+t; i < N; i += 256*256)
      atomicAdd(&hist[gid[i]], 1);
    __syncthreads();
    if (hist[t]) atomicAdd(&gcnt[t], (float)hist[t]);
  } else {
    int bb = b - (NC+512);
    int n = bb & 127;
    int layer = bb >> 7;
    const float* ws = layer? ws1 : ws0;
    const float* wn = layer? wn1 : wn0;
    float v = (t<128)? ws[t*DF+n] : wn[(t-128)*DF+n];
    wt[((size_t)layer*DF + n)*256 + t] = __bfloat16_as_ushort(__float2bfloat16(v));
  }
}

// =============== k_place1: gather (blocks [0,NP1)) + mega-binning ([NP1,NP1+256)) ===============
// Mega-bucket = dst>>14 (16K nodes, <=7 buckets). Per (block,mb) stores are a
// CONTIGUOUS run (~1KB) -> ~64x fewer line-RFOs than 4B random scatter (the
// R15-diagnosed 61us bottleneck). pairs1 entry: src<<14 | (dst&16383).
__global__ __launch_bounds__(256)
void k_place1(const int* __restrict__ feat, const unsigned* __restrict__ emb_f8,
              unsigned* __restrict__ h_f8, int N,
              const int* __restrict__ src, const int* __restrict__ dst,
              const int* __restrict__ gb, int* __restrict__ mbcur,
              unsigned* __restrict__ pairs1, int E, int NP1){
  const int b = blockIdx.x, t = threadIdx.x;
  if (b < NP1){
    int idx = b*256 + t;   // uint4 chunk (16 fp8)
    int total = N*8;
    if (idx<total){
      int i = idx>>3, c = idx&7;
      ((uint4*)h_f8)[idx] = ((const uint4*)emb_f8)[(size_t)feat[i]*8 + c];
    }
    return;
  }
  __shared__ int sgb[256];
  __shared__ int mbstart[8];
  __shared__ int hist1[8];
  __shared__ int base1[8];
  __shared__ int cur1[8];
  const int bb = b - NP1;
  const int CH = (E + 255)/256;
  const int s = bb*CH;
  int e = s+CH; if (e>E) e=E;
  if (s>=E) return;
  int v = gb[t];
  sgb[t]=v;
  if (t<8){ hist1[t]=0; cur1[t]=0; }
  __syncthreads();
  for (int o=1;o<256;o<<=1){
    int x = (t>=o)? sgb[t-o] : 0;
    __syncthreads();
    sgb[t]+=x;
    __syncthreads();
  }
  if ((t&31)==0) mbstart[t>>5] = sgb[t]-v;   // exclusive prefix at fine m*32
  __syncthreads();
  for (int i=s+t; i<e; i+=256) atomicAdd(&hist1[dst[i]>>14],1);
  __syncthreads();
  if (t<8 && hist1[t]) base1[t] = mbstart[t] + atomicAdd(&mbcur[t],hist1[t]);
  __syncthreads();
  for (int i=s+t; i<e; i+=256){
    int d = dst[i];
    int m = d>>14;
    int r = atomicAdd(&cur1[m],1);
    pairs1[base1[m]+r] = ((unsigned)src[i]<<14) | (unsigned)(d & 16383);
  }
}

// =============== k_place2: fine-binning within megabucket segments ===============
// block b: megabucket m=b/BPM, sub-chunk b%BPM. Runs ~200+ entries per
// (block,fine) -> line-friendly. Emits src<<9|dst&511 (k_bcsr format).
__global__ __launch_bounds__(256)
void k_place2(const unsigned* __restrict__ pairs1, const int* __restrict__ gb,
              int* __restrict__ fcur, unsigned* __restrict__ pairs2, int E){
  __shared__ int sgb[256];
  __shared__ int fstart[32];
  __shared__ int segS_l, segE_l;
  __shared__ int hist2[32];
  __shared__ int base2[32];
  __shared__ int cur2[32];
  const int t = threadIdx.x;
  const int m = blockIdx.x / BPM;
  const int sub = blockIdx.x % BPM;
  int v = gb[t];
  sgb[t]=v;
  if (t<32){ hist2[t]=0; cur2[t]=0; }
  __syncthreads();
  for (int o=1;o<256;o<<=1){
    int x = (t>=o)? sgb[t-o] : 0;
    __syncthreads();
    sgb[t]+=x;
    __syncthreads();
  }
  {
    int f0 = m*32;
    if (t>=f0 && t<f0+32) fstart[t-f0] = sgb[t]-v;   // excl prefix of fine t
    if (t==f0) segS_l = sgb[t]-v;
    int f1 = f0+32;
    if (f1 < 256){ if (t==f1) segE_l = sgb[t]-v; }
    else { if (t==0) segE_l = E; }
  }
  __syncthreads();
  const int segS = segS_l, segE = segE_l;
  const int segLen = segE - segS;
  if (segLen<=0) return;
  const int CH2 = (segLen + BPM-1)/BPM;
  const int s = segS + sub*CH2;
  int e = s+CH2; if (e>segE) e=segE;
  if (s>=segE) return;
  for (int i=s+t; i<e; i+=256) atomicAdd(&hist2[(pairs1[i]&16383u)>>9],1);
  __syncthreads();
  if (t<32 && hist2[t]) base2[t] = fstart[t] + atomicAdd(&fcur[m*32+t],hist2[t]);
  __syncthreads();
  for (int i=s+t; i<e; i+=256){
    unsigned p = pairs1[i];
    unsigned d14 = p & 16383u;
    int f = d14>>9;
    int r = atomicAdd(&cur2[f],1);
    pairs2[base2[f]+r] = ((p>>14)<<9) | (d14 & 511u);
  }
}

__global__ __launch_bounds__(256)
void k_bcsr(const unsigned* __restrict__ pairs, const int* __restrict__ gb,
            int* __restrict__ offs, int* __restrict__ csr, int N, int E){
  __shared__ int sgb[256];
  __shared__ int ncnt[512];
  __shared__ int noff[512];
  __shared__ int sh[256];
  const int t = threadIdx.x;
  const int b = blockIdx.x;
  const int nb0 = b<<9;
  int v = gb[t];
  sgb[t]=v;
  ncnt[t]=0; ncnt[t+256]=0;
  __syncthreads();
  for (int o=1;o<256;o<<=1){
    int x = (t>=o)? sgb[t-o] : 0;
    __syncthreads();
    sgb[t]+=x;
    __syncthreads();
  }
  const int s = sgb[b]-gb[b];   // bucket b start
  const int e = sgb[b];         // bucket b end
  for (int i=s+t; i<e; i+=256) atomicAdd(&ncnt[pairs[i] & 511u], 1);
  __syncthreads();
  int v0 = ncnt[2*t], v1 = ncnt[2*t+1];
  int vv = v0+v1;
  sh[t]=vv; __syncthreads();
  for (int o=1;o<256;o<<=1){
    int x=(t>=o)?sh[t-o]:0;
    __syncthreads();
    sh[t]+=x;
    __syncthreads();
  }
  int ex = sh[t]-vv;
  noff[2*t]=ex; noff[2*t+1]=ex+v0;
  __syncthreads();
  {
    int n0 = nb0 + t;
    if (n0 < N) offs[n0] = s + noff[t];
    int n1 = nb0 + t + 256;
    if (n1 < N) offs[n1] = s + noff[t+256];
    if (b == gridDim.x-1 && t==0) offs[N] = E;
  }
  ncnt[t]=0; ncnt[t+256]=0;
  __syncthreads();
  for (int i=s+t; i<e; i+=256){
    unsigned p = pairs[i];
    int d = p & 511u;
    int r = atomicAdd(&ncnt[d],1);
    csr[s + noff[d] + r] = (int)(p >> 9);
  }
}

// ---------------- fused SAGE layer: fp8-only h, LDS-staged csr, MFMA GEMM ----------------
template<int MODE>
__global__ __launch_bounds__(256,8)
void k_sage(const unsigned char* __restrict__ h_in_f8,
            const int* __restrict__ offs, const int* __restrict__ csr,
            const unsigned short* __restrict__ wt,
            const float* __restrict__ bias,
            unsigned char* __restrict__ h_out_f8,
            const int* __restrict__ gid, float* __restrict__ gsum, int N){
  __shared__ __align__(16) unsigned short s_ab[32*256];   // 16KB
  __shared__ int s_csr[CSR_CAP];
  __shared__ int s_gid[32];
  __shared__ float s_tmp[DF];
  const int t = threadIdx.x;
  const int node0 = blockIdx.x*32;
  const uint4* f8r = (const uint4*)h_in_f8;   // 8 uint4 per fp8 row

  if (MODE==1 && t<32) s_gid[t] = (node0+t<N)? gid[node0+t] : -1;

  // ---- stage block csr slice (contiguous, coalesced)
  const int eBase = offs[node0];
  const int eTop  = offs[min(node0+32, N)];
  const int ecount = eTop - eBase;
  const bool useLds = (ecount <= CSR_CAP);
  if (useLds){
    for (int i=t; i<ecount; i+=256) s_csr[i] = csr[eBase+i];
  }

  const int nn = t>>3, c = t&7;
  const int sw = (nn&7)<<4;

  // ---- self row chunk: fp8 load -> bf16 unpack -> A-tile cols 0..127, swizzled
  {
    int node = node0+nn;
    uint4 q = make_uint4(0,0,0,0);
    if (node<N) q = f8r[(size_t)node*8 + c];
    f32x2 u; unsigned pk[8];
    u=__builtin_amdgcn_cvt_pk_f32_fp8(q.x,false); pk[0]=pack2bf(u[0],u[1]);
    u=__builtin_amdgcn_cvt_pk_f32_fp8(q.x,true ); pk[1]=pack2bf(u[0],u[1]);
    u=__builtin_amdgcn_cvt_pk_f32_fp8(q.y,false); pk[2]=pack2bf(u[0],u[1]);
    u=__builtin_amdgcn_cvt_pk_f32_fp8(q.y,true ); pk[3]=pack2bf(u[0],u[1]);
    u=__builtin_amdgcn_cvt_pk_f32_fp8(q.z,false); pk[4]=pack2bf(u[0],u[1]);
    u=__builtin_amdgcn_cvt_pk_f32_fp8(q.z,true ); pk[5]=pack2bf(u[0],u[1]);
    u=__builtin_amdgcn_cvt_pk_f32_fp8(q.w,false); pk[6]=pack2bf(u[0],u[1]);
    u=__builtin_amdgcn_cvt_pk_f32_fp8(q.w,true ); pk[7]=pack2bf(u[0],u[1]);
    int byte0 = nn*512 + c*32;
    *(uint4*)((char*)s_ab + ((byte0   )^sw)) = make_uint4(pk[0],pk[1],pk[2],pk[3]);
    *(uint4*)((char*)s_ab + ((byte0+16)^sw)) = make_uint4(pk[4],pk[5],pk[6],pk[7]);
  }
  __syncthreads();   // s_csr ready

  // ---- neighbor mean from fp8 rows: idx from LDS, 2-edge unroll
  {
    const int node = node0+nn;
    float a[16];
    #pragma unroll
    for (int j=0;j<16;j++) a[j]=0.f;
    if (node<N){
      int e0=offs[node], e1=offs[node+1];
      int deg = e1-e0;
      if (deg>0){
        #define ACC16(q) { \
          f32x2 u; \
          u=__builtin_amdgcn_cvt_pk_f32_fp8((q).x,false); a[0]+=u[0]; a[1]+=u[1]; \
          u=__builtin_amdgcn_cvt_pk_f32_fp8((q).x,true ); a[2]+=u[0]; a[3]+=u[1]; \
          u=__builtin_amdgcn_cvt_pk_f32_fp8((q).y,false); a[4]+=u[0]; a[5]+=u[1]; \
          u=__builtin_amdgcn_cvt_pk_f32_fp8((q).y,true ); a[6]+=u[0]; a[7]+=u[1]; \
          u=__builtin_amdgcn_cvt_pk_f32_fp8((q).z,false); a[8]+=u[0]; a[9]+=u[1]; \
          u=__builtin_amdgcn_cvt_pk_f32_fp8((q).z,true ); a[10]+=u[0]; a[11]+=u[1]; \
          u=__builtin_amdgcn_cvt_pk_f32_fp8((q).w,false); a[12]+=u[0]; a[13]+=u[1]; \
          u=__builtin_amdgcn_cvt_pk_f32_fp8((q).w,true ); a[14]+=u[0]; a[15]+=u[1]; }
        if (useLds){
          int le = e0 - eBase, le1 = e1 - eBase;
          for (; le+2<=le1; le+=2){
            int s0 = s_csr[le], s1 = s_csr[le+1];
            uint4 q0 = f8r[(size_t)s0*8 + c];
            uint4 q1 = f8r[(size_t)s1*8 + c];
            ACC16(q0); ACC16(q1);
          }
          if (le<le1){
            uint4 q0 = f8r[(size_t)s_csr[le]*8 + c];
            ACC16(q0);
          }
        } else {
          int e = e0;
          for (; e+2<=e1; e+=2){
            int s0 = csr[e], s1 = csr[e+1];
            uint4 q0 = f8r[(size_t)s0*8 + c];
            uint4 q1 = f8r[(size_t)s1*8 + c];
            ACC16(q0); ACC16(q1);
          }
          if (e<e1){
            uint4 q0 = f8r[(size_t)csr[e]*8 + c];
            ACC16(q0);
          }
        }
        #undef ACC16
        float inv = 1.0f/(float)deg;
        #pragma unroll
        for (int j=0;j<16;j++) a[j]*=inv;
      }
    }
    unsigned pk[8];
    #pragma unroll
    for (int j=0;j<8;j++) pk[j] = pack2bf(a[2*j],a[2*j+1]);
    int byte0 = nn*512 + 256 + c*32;
    *(uint4*)((char*)s_ab + ((byte0   )^sw)) = make_uint4(pk[0],pk[1],pk[2],pk[3]);
    *(uint4*)((char*)s_ab + ((byte0+16)^sw)) = make_uint4(pk[4],pk[5],pk[6],pk[7]);
  }

  const int wv = t>>6;
  const int lr = t&15;
  const int kg = (t&63)>>4;
  __syncthreads();

  // ---- MFMA main loop, B loaded per K-half from global (L2-resident)
  f32x4 acc00={0,0,0,0}, acc01={0,0,0,0}, acc10={0,0,0,0}, acc11={0,0,0,0};
  const s8v* wt8 = (const s8v*)wt;
  #pragma unroll
  for (int kh=0; kh<2; kh++){
    s8v bfrag[2][4];
    #pragma unroll
    for (int ks=0; ks<4; ks++){
      int kb = (kh*4+ks)*4 + kg;
      bfrag[0][ks] = wt8[(size_t)(wv*32     + lr)*32 + kb];
      bfrag[1][ks] = wt8[(size_t)(wv*32 + 16+ lr)*32 + kb];
    }
    #pragma unroll
    for (int ks=0; ks<4; ks++){
      int cb = (kh*4+ks)*64 + kg*16;
      int r0 = lr, r1 = 16+lr;
      s8v a0 = *(const s8v*)((const char*)s_ab + ((r0*512+cb) ^ ((r0&7)<<4)));
      s8v a1 = *(const s8v*)((const char*)s_ab + ((r1*512+cb) ^ ((r1&7)<<4)));
      acc00 = __builtin_amdgcn_mfma_f32_16x16x32_bf16(a0, bfrag[0][ks], acc00, 0,0,0);
      acc01 = __builtin_amdgcn_mfma_f32_16x16x32_bf16(a0, bfrag[1][ks], acc01, 0,0,0);
      acc10 = __builtin_amdgcn_mfma_f32_16x16x32_bf16(a1, bfrag[0][ks], acc10, 0,0,0);
      acc11 = __builtin_amdgcn_mfma_f32_16x16x32_bf16(a1, bfrag[1][ks], acc11, 0,0,0);
    }
  }
  __syncthreads();

  // ---- epilogue: acc -> LDS f32 [32][128]
  float* cbuf = (float*)s_ab;
  #pragma unroll
  for (int r=0;r<4;r++){
    int row0 = kg*4 + r;
    cbuf[(row0   )*DF + wv*32      + lr] = acc00[r];
    cbuf[(row0   )*DF + wv*32 + 16 + lr] = acc01[r];
    cbuf[(row0+16)*DF + wv*32      + lr] = acc10[r];
    cbuf[(row0+16)*DF + wv*32 + 16 + lr] = acc11[r];
  }
  __syncthreads();

  if (MODE==0){
    int row = t>>3, c0 = (t&7)*16;
    int node = node0+row;
    if (node<N){
      float x[16];
      #pragma unroll
      for (int j=0;j<16;j++) x[j] = fmaxf(cbuf[row*DF + c0 + j] + bias[c0+j], 0.f);
      unsigned f0 = __builtin_amdgcn_cvt_pk_fp8_f32(x[0], x[1], 0, false);
      f0 = __builtin_amdgcn_cvt_pk_fp8_f32(x[2], x[3], f0, true);
      unsigned f1 = __builtin_amdgcn_cvt_pk_fp8_f32(x[4], x[5], 0, false);
      f1 = __builtin_amdgcn_cvt_pk_fp8_f32(x[6], x[7], f1, true);
      unsigned f2 = __builtin_amdgcn_cvt_pk_fp8_f32(x[8], x[9], 0, false);
      f2 = __builtin_amdgcn_cvt_pk_fp8_f32(x[10], x[11], f2, true);
      unsigned f3 = __builtin_amdgcn_cvt_pk_fp8_f32(x[12], x[13], 0, false);
      f3 = __builtin_amdgcn_cvt_pk_fp8_f32(x[14], x[15], f3, true);
      *(uint4*)&h_out_f8[(size_t)node*DF + c0] = make_uint4(f0,f1,f2,f3);
    }
  } else {
    // fused pool: segment loop over sorted gid runs; one atomic per (segment,d)
    const int d = t&127, rh = t>>7;
    const float bd = bias[d];
    int segStart = 0;
    while (segStart < 32 && s_gid[segStart] >= 0){
      int g = s_gid[segStart];
      int segEnd = segStart+1;
      while (segEnd < 32 && s_gid[segEnd] == g) segEnd++;
      float p = 0.f;
      for (int r = segStart+rh; r < segEnd; r += 2)
        p += fmaxf(cbuf[r*DF + d] + bd, 0.f);
      if (rh==1) s_tmp[d] = p;
      __syncthreads();
      if (rh==0) atomicAdd(&gsum[g*DF+d], p + s_tmp[d]);
      __syncthreads();
      segStart = segEnd;
    }
  }
}

// ---------------- fused MLP head ----------------
__global__ __launch_bounds__(256)
void k_head(const float* __restrict__ gsum, const float* __restrict__ gcnt,
            const float* __restrict__ e1w, const float* __restrict__ e1b,
            const float* __restrict__ e2w, const float* __restrict__ e2b,
            const float* __restrict__ e3w, const float* __restrict__ e3b,
            const float* __restrict__ e4w, const float* __restrict__ e4b,
            const float* __restrict__ pw,  const float* __restrict__ pb,
            float* __restrict__ out, float* __restrict__ hidden){
  __shared__ float hg[DF];
  __shared__ float bufA[HID];
  __shared__ float bufB[HID];
  __shared__ float r0[HID], r1[HID];
  const int g = blockIdx.x, t = threadIdx.x;
  if (t<DF) hg[t] = gsum[g*DF+t] / fmaxf(gcnt[g],1.0f);
  __syncthreads();

  float acc = e1b[t];
  for (int k=0;k<DF;++k) acc += hg[k]*e1w[k*HID+t];
  float h1 = fmaxf(acc,0.f);
  hidden[g*HID+t] = h1;
  bufA[t] = h1;
  __syncthreads();

  acc = e2b[t];
  for (int k=0;k<HID;++k) acc += bufA[k]*e2w[k*HID+t];
  bufB[t] = fmaxf(acc,0.f);
  __syncthreads();

  acc = e3b[t];
  for (int k=0;k<HID;++k) acc += bufB[k]*e3w[k*HID+t];
  bufA[t] = fmaxf(acc,0.f);
  __syncthreads();

  acc = e4b[t];
  for (int k=0;k<HID;++k) acc += bufA[k]*e4w[k*HID+t];
  float h4 = fmaxf(acc,0.f);

  r0[t] = h4*pw[t*2+0];
  r1[t] = h4*pw[t*2+1];
  __syncthreads();
  for (int o=128;o>0;o>>=1){
    if (t<o){ r0[t]+=r0[t+o]; r1[t]+=r1[t+o]; }
    __syncthreads();
  }
  if (t==0){
    float y0 = r0[0]+pb[0], y1 = r1[0]+pb[1];
    float m = fmaxf(y0,y1);
    float l = m + logf(expf(y0-m)+expf(y1-m));
    out[g*2+0]=y0-l;
    out[g*2+1]=y1-l;
  }
}

extern "C" void kernel_launch(void* const* d_in, const int* in_sizes, int n_in,
                              void* d_out, int out_size, void* d_ws, size_t ws_size,
                              hipStream_t stream){
  const int* feat = (const int*)d_in[0];
  const int* src  = (const int*)d_in[1];
  const int* dst  = (const int*)d_in[2];
  const int* gid  = (const int*)d_in[3];
  const float* emb = (const float*)d_in[4];
  const float* ws0 = (const float*)d_in[5];
  const float* wn0 = (const float*)d_in[6];
  const float* b0  = (const float*)d_in[7];
  const float* ws1 = (const float*)d_in[8];
  const float* wn1 = (const float*)d_in[9];
  const float* b1  = (const float*)d_in[10];
  const float* e1w = (const float*)d_in[11];
  const float* e1b = (const float*)d_in[12];
  const float* e2w = (const float*)d_in[13];
  const float* e2b = (const float*)d_in[14];
  const float* e3w = (const float*)d_in[15];
  const float* e3b = (const float*)d_in[16];
  const float* e4w = (const float*)d_in[17];
  const float* e4b = (const float*)d_in[18];
  const float* pw  = (const float*)d_in[19];
  const float* pb  = (const float*)d_in[20];
  const int N = in_sizes[0];
  const int E = in_sizes[1];
  const int nvoc = in_sizes[4] / DF;

  char* basep = (char*)d_ws;
  size_t off=0;
  auto alloc=[&](size_t bytes)->void*{
    void* p = basep+off; off=(off+bytes+255)&~(size_t)255; return p;
  };
  unsigned char*  hA_f8 = (unsigned char*) alloc((size_t)N*DF);
  unsigned char*  hB_f8 = (unsigned char*) alloc((size_t)N*DF);
  unsigned char*  emb_f8= (unsigned char*) alloc((size_t)nvoc*DF);
  int*   offs  = (int*)  alloc((size_t)(N+1)*4);
  int*   csr   = (int*)  alloc((size_t)E*4);
  int*   gb    = (int*)  alloc(1024);
  int*   mbcur = (int*)  alloc(1024);
  int*   fcur  = (int*)  alloc(1024);
  unsigned short* wtb = (unsigned short*)alloc((size_t)2*DF*256*2);
  float* gsum  = (float*)alloc((size_t)NG*DF*4);
  float* gcnt  = (float*)alloc((size_t)NG*4);
  unsigned* pairs1 = (unsigned*)alloc((size_t)E*4);
  unsigned* pairs2 = (unsigned*)alloc((size_t)E*4);
  float* out    = (float*)d_out;
  float* hidden = out + NG*2;

  hipMemsetAsync(gb, 0, 1024, stream);
  hipMemsetAsync(mbcur, 0, 1024, stream);
  hipMemsetAsync(fcur, 0, 1024, stream);
  hipMemsetAsync(gsum, 0, (size_t)NG*DF*4, stream);
  hipMemsetAsync(gcnt, 0, (size_t)NG*4, stream);

  const int NBK = (N+511)>>9;               // fine buckets (512 nodes)
  const int NBMB = (N+16383)>>14;           // megabuckets (16K nodes)
  const int NC = (nvoc*(DF/8) + 255)/256;   // emb-convert blocks
  const int NP1 = (N*8 + 255)/256;          // gather blocks
  k_pre0<<<NC+768,256,0,stream>>>(emb,(unsigned*)emb_f8,nvoc,
                                  dst,gb,gid,gcnt,
                                  ws0,wn0,ws1,wn1,wtb,N,E,NC);
  k_place1<<<NP1+256,256,0,stream>>>(feat,(const unsigned*)emb_f8,
                                     (unsigned*)hA_f8,N,
                                     src,dst,gb,mbcur,pairs1,E,NP1);
  k_place2<<<NBMB*BPM,256,0,stream>>>(pairs1,gb,fcur,pairs2,E);
  k_bcsr<<<NBK,256,0,stream>>>(pairs2,gb,offs,csr,N,E);

  k_sage<0><<<(N+31)/32,256,0,stream>>>(hA_f8,offs,csr,wtb,        b0,
                                        hB_f8,nullptr,nullptr,N);
  k_sage<1><<<(N+31)/32,256,0,stream>>>(hB_f8,offs,csr,wtb+DF*256, b1,
                                        nullptr,gid,gsum,N);

  k_head<<<NG,HID,0,stream>>>(gsum,gcnt,e1w,e1b,e2w,e2b,e3w,e3b,e4w,e4b,
                              pw,pb,out,hidden);
}

// Round 17
// 207.003 us; speedup vs baseline: 1.1396x; 1.0852x over previous
//
#include <hip/hip_runtime.h>
#include <hip/hip_bf16.h>
#include <math.h>

#define DF 128
#define HID 256
#define NG 256
#define CSR_CAP 768

typedef __attribute__((ext_vector_type(8))) short s8v;    // 8 bf16 (4 VGPR)
typedef __attribute__((ext_vector_type(4))) float f32x4;  // MFMA acc
typedef __attribute__((ext_vector_type(2))) float f32x2;

__device__ __forceinline__ unsigned pack2bf(float lo, float hi){
  unsigned a = __bfloat16_as_ushort(__float2bfloat16(lo));
  unsigned b = __bfloat16_as_ushort(__float2bfloat16(hi));
  return a | (b<<16);
}

// =============== k_pre0: emb table f32->fp8 (streamed) + hists + weight prep ===============
__global__ __launch_bounds__(256)
void k_pre0(const float* __restrict__ emb, unsigned* __restrict__ emb_f8, int nvoc,
            const int* __restrict__ dst, int* __restrict__ gb,
            const int* __restrict__ gid, float* __restrict__ gcnt,
            const float* __restrict__ ws0, const float* __restrict__ wn0,
            const float* __restrict__ ws1, const float* __restrict__ wn1,
            unsigned short* __restrict__ wt,
            int N, int E, int NC){
  __shared__ int hist[256];
  const int b = blockIdx.x, t = threadIdx.x;
  if (b < NC){
    int idx = b*256 + t;                 // 8-elem chunk (uint2 of fp8)
    int total = nvoc*(DF/8);
    if (idx<total){
      const float4* e4 = (const float4*)emb;
      float4 v0 = e4[(size_t)idx*2], v1 = e4[(size_t)idx*2+1];
      unsigned w0 = __builtin_amdgcn_cvt_pk_fp8_f32(v0.x, v0.y, 0, false);
      w0 = __builtin_amdgcn_cvt_pk_fp8_f32(v0.z, v0.w, w0, true);
      unsigned w1 = __builtin_amdgcn_cvt_pk_fp8_f32(v1.x, v1.y, 0, false);
      w1 = __builtin_amdgcn_cvt_pk_fp8_f32(v1.z, v1.w, w1, true);
      ((uint2*)emb_f8)[idx] = make_uint2(w0,w1);
    }
  } else if (b < NC+256){
    int bb = b - NC;
    hist[t]=0; __syncthreads();
    for (int i = bb*256+t; i < E; i += 256*256)
      atomicAdd(&hist[dst[i]>>9], 1);
    __syncthreads();
    if (hist[t]) atomicAdd(&gb[t], hist[t]);
  } else if (b < NC+512){
    int bb = b - (NC+256);
    hist[t]=0; __syncthreads();
    for (int i = bb*256+t; i < N; i += 256*256)
      atomicAdd(&hist[gid[i]], 1);
    __syncthreads();
    if (hist[t]) atomicAdd(&gcnt[t], (float)hist[t]);
  } else {
    int bb = b - (NC+512);
    int n = bb & 127;
    int layer = bb >> 7;
    const float* ws = layer? ws1 : ws0;
    const float* wn = layer? wn1 : wn0;
    float v = (t<128)? ws[t*DF+n] : wn[(t-128)*DF+n];
    wt[((size_t)layer*DF + n)*256 + t] = __bfloat16_as_ushort(__float2bfloat16(v));
  }
}

// =============== k_mid: binning FIRST (blocks [0,256)) + gather ([256,256+NP1)) ===============
// R14 fused structure, but binning blocks launch first so the long-pole
// scatter starts immediately; gather fills the machine around it.
__global__ __launch_bounds__(256)
void k_mid(const int* __restrict__ feat, const unsigned* __restrict__ emb_f8,
           unsigned* __restrict__ h_f8, int N,
           const int* __restrict__ src, const int* __restrict__ dst,
           const int* __restrict__ gb, int* __restrict__ bcur,
           unsigned* __restrict__ pairs, int E){
  const int b = blockIdx.x, t = threadIdx.x;
  if (b >= 256){
    int idx = (b-256)*256 + t;   // uint4 chunk (16 fp8)
    int total = N*8;
    if (idx<total){
      int i = idx>>3, c = idx&7;
      ((uint4*)h_f8)[idx] = ((const uint4*)emb_f8)[(size_t)feat[i]*8 + c];
    }
    return;
  }
  __shared__ int sgb[256];
  __shared__ int hist[256];
  __shared__ int base[256];
  __shared__ int cur[256];
  const int CH = (E + 255)/256;
  const int s = b*CH;
  int e = s+CH; if (e>E) e=E;
  if (s>=E) return;
  int v = gb[t];
  sgb[t]=v;
  hist[t]=0;
  __syncthreads();
  for (int o=1;o<256;o<<=1){
    int x = (t>=o)? sgb[t-o] : 0;
    __syncthreads();
    sgb[t]+=x;
    __syncthreads();
  }
  int bstart = sgb[t]-v;   // exclusive prefix = bucket t start
  for (int i=s+t; i<e; i+=256) atomicAdd(&hist[dst[i]>>9],1);
  __syncthreads();
  if (hist[t]){ base[t] = bstart + atomicAdd(&bcur[t],hist[t]); }
  cur[t]=0;
  __syncthreads();
  for (int i=s+t; i<e; i+=256){
    int d = dst[i];
    int bk = d>>9;
    int r = atomicAdd(&cur[bk],1);
    pairs[base[bk]+r] = ((unsigned)src[i]<<9) | (unsigned)(d & 511);
  }
}

__global__ __launch_bounds__(256)
void k_bcsr(const unsigned* __restrict__ pairs, const int* __restrict__ gb,
            int* __restrict__ offs, int* __restrict__ csr, int N, int E){
  __shared__ int sgb[256];
  __shared__ int ncnt[512];
  __shared__ int noff[512];
  __shared__ int sh[256];
  const int t = threadIdx.x;
  const int b = blockIdx.x;
  const int nb0 = b<<9;
  int v = gb[t];
  sgb[t]=v;
  ncnt[t]=0; ncnt[t+256]=0;
  __syncthreads();
  for (int o=1;o<256;o<<=1){
    int x = (t>=o)? sgb[t-o] : 0;
    __syncthreads();
    sgb[t]+=x;
    __syncthreads();
  }
  const int s = sgb[b]-gb[b];   // bucket b start
  const int e = sgb[b];         // bucket b end
  for (int i=s+t; i<e; i+=256) atomicAdd(&ncnt[pairs[i] & 511u], 1);
  __syncthreads();
  int v0 = ncnt[2*t], v1 = ncnt[2*t+1];
  int vv = v0+v1;
  sh[t]=vv; __syncthreads();
  for (int o=1;o<256;o<<=1){
    int x=(t>=o)?sh[t-o]:0;
    __syncthreads();
    sh[t]+=x;
    __syncthreads();
  }
  int ex = sh[t]-vv;
  noff[2*t]=ex; noff[2*t+1]=ex+v0;
  __syncthreads();
  {
    int n0 = nb0 + t;
    if (n0 < N) offs[n0] = s + noff[t];
    int n1 = nb0 + t + 256;
    if (n1 < N) offs[n1] = s + noff[t+256];
    if (b == gridDim.x-1 && t==0) offs[N] = E;
  }
  ncnt[t]=0; ncnt[t+256]=0;
  __syncthreads();
  for (int i=s+t; i<e; i+=256){
    unsigned p = pairs[i];
    int d = p & 511u;
    int r = atomicAdd(&ncnt[d],1);
    csr[s + noff[d] + r] = (int)(p >> 9);
  }
}

// ---------------- fused SAGE layer: fp8-only h, LDS-staged csr, MFMA GEMM ----------------
template<int MODE>
__global__ __launch_bounds__(256,8)
void k_sage(const unsigned char* __restrict__ h_in_f8,
            const int* __restrict__ offs, const int* __restrict__ csr,
            const unsigned short* __restrict__ wt,
            const float* __restrict__ bias,
            unsigned char* __restrict__ h_out_f8,
            const int* __restrict__ gid, float* __restrict__ gsum, int N){
  __shared__ __align__(16) unsigned short s_ab[32*256];   // 16KB
  __shared__ int s_csr[CSR_CAP];
  __shared__ int s_gid[32];
  __shared__ float s_tmp[DF];
  const int t = threadIdx.x;
  const int node0 = blockIdx.x*32;
  const uint4* f8r = (const uint4*)h_in_f8;   // 8 uint4 per fp8 row

  if (MODE==1 && t<32) s_gid[t] = (node0+t<N)? gid[node0+t] : -1;

  // ---- stage block csr slice (contiguous, coalesced)
  const int eBase = offs[node0];
  const int eTop  = offs[min(node0+32, N)];
  const int ecount = eTop - eBase;
  const bool useLds = (ecount <= CSR_CAP);
  if (useLds){
    for (int i=t; i<ecount; i+=256) s_csr[i] = csr[eBase+i];
  }

  const int nn = t>>3, c = t&7;
  const int sw = (nn&7)<<4;

  // ---- self row chunk: fp8 load -> bf16 unpack -> A-tile cols 0..127, swizzled
  {
    int node = node0+nn;
    uint4 q = make_uint4(0,0,0,0);
    if (node<N) q = f8r[(size_t)node*8 + c];
    f32x2 u; unsigned pk[8];
    u=__builtin_amdgcn_cvt_pk_f32_fp8(q.x,false); pk[0]=pack2bf(u[0],u[1]);
    u=__builtin_amdgcn_cvt_pk_f32_fp8(q.x,true ); pk[1]=pack2bf(u[0],u[1]);
    u=__builtin_amdgcn_cvt_pk_f32_fp8(q.y,false); pk[2]=pack2bf(u[0],u[1]);
    u=__builtin_amdgcn_cvt_pk_f32_fp8(q.y,true ); pk[3]=pack2bf(u[0],u[1]);
    u=__builtin_amdgcn_cvt_pk_f32_fp8(q.z,false); pk[4]=pack2bf(u[0],u[1]);
    u=__builtin_amdgcn_cvt_pk_f32_fp8(q.z,true ); pk[5]=pack2bf(u[0],u[1]);
    u=__builtin_amdgcn_cvt_pk_f32_fp8(q.w,false); pk[6]=pack2bf(u[0],u[1]);
    u=__builtin_amdgcn_cvt_pk_f32_fp8(q.w,true ); pk[7]=pack2bf(u[0],u[1]);
    int byte0 = nn*512 + c*32;
    *(uint4*)((char*)s_ab + ((byte0   )^sw)) = make_uint4(pk[0],pk[1],pk[2],pk[3]);
    *(uint4*)((char*)s_ab + ((byte0+16)^sw)) = make_uint4(pk[4],pk[5],pk[6],pk[7]);
  }
  __syncthreads();   // s_csr ready

  // ---- neighbor mean from fp8 rows: idx from LDS, 2-edge unroll
  {
    const int node = node0+nn;
    float a[16];
    #pragma unroll
    for (int j=0;j<16;j++) a[j]=0.f;
    if (node<N){
      int e0=offs[node], e1=offs[node+1];
      int deg = e1-e0;
      if (deg>0){
        #define ACC16(q) { \
          f32x2 u; \
          u=__builtin_amdgcn_cvt_pk_f32_fp8((q).x,false); a[0]+=u[0]; a[1]+=u[1]; \
          u=__builtin_amdgcn_cvt_pk_f32_fp8((q).x,true ); a[2]+=u[0]; a[3]+=u[1]; \
          u=__builtin_amdgcn_cvt_pk_f32_fp8((q).y,false); a[4]+=u[0]; a[5]+=u[1]; \
          u=__builtin_amdgcn_cvt_pk_f32_fp8((q).y,true ); a[6]+=u[0]; a[7]+=u[1]; \
          u=__builtin_amdgcn_cvt_pk_f32_fp8((q).z,false); a[8]+=u[0]; a[9]+=u[1]; \
          u=__builtin_amdgcn_cvt_pk_f32_fp8((q).z,true ); a[10]+=u[0]; a[11]+=u[1]; \
          u=__builtin_amdgcn_cvt_pk_f32_fp8((q).w,false); a[12]+=u[0]; a[13]+=u[1]; \
          u=__builtin_amdgcn_cvt_pk_f32_fp8((q).w,true ); a[14]+=u[0]; a[15]+=u[1]; }
        if (useLds){
          int le = e0 - eBase, le1 = e1 - eBase;
          for (; le+2<=le1; le+=2){
            int s0 = s_csr[le], s1 = s_csr[le+1];
            uint4 q0 = f8r[(size_t)s0*8 + c];
            uint4 q1 = f8r[(size_t)s1*8 + c];
            ACC16(q0); ACC16(q1);
          }
          if (le<le1){
            uint4 q0 = f8r[(size_t)s_csr[le]*8 + c];
            ACC16(q0);
          }
        } else {
          int e = e0;
          for (; e+2<=e1; e+=2){
            int s0 = csr[e], s1 = csr[e+1];
            uint4 q0 = f8r[(size_t)s0*8 + c];
            uint4 q1 = f8r[(size_t)s1*8 + c];
            ACC16(q0); ACC16(q1);
          }
          if (e<e1){
            uint4 q0 = f8r[(size_t)csr[e]*8 + c];
            ACC16(q0);
          }
        }
        #undef ACC16
        float inv = 1.0f/(float)deg;
        #pragma unroll
        for (int j=0;j<16;j++) a[j]*=inv;
      }
    }
    unsigned pk[8];
    #pragma unroll
    for (int j=0;j<8;j++) pk[j] = pack2bf(a[2*j],a[2*j+1]);
    int byte0 = nn*512 + 256 + c*32;
    *(uint4*)((char*)s_ab + ((byte0   )^sw)) = make_uint4(pk[0],pk[1],pk[2],pk[3]);
    *(uint4*)((char*)s_ab + ((byte0+16)^sw)) = make_uint4(pk[4],pk[5],pk[6],pk[7]);
  }

  const int wv = t>>6;
  const int lr = t&15;
  const int kg = (t&63)>>4;
  __syncthreads();

  // ---- MFMA main loop, B loaded per K-half from global (L2-resident)
  f32x4 acc00={0,0,0,0}, acc01={0,0,0,0}, acc10={0,0,0,0}, acc11={0,0,0,0};
  const s8v* wt8 = (const s8v*)wt;
  #pragma unroll
  for (int kh=0; kh<2; kh++){
    s8v bfrag[2][4];
    #pragma unroll
    for (int ks=0; ks<4; ks++){
      int kb = (kh*4+ks)*4 + kg;
      bfrag[0][ks] = wt8[(size_t)(wv*32     + lr)*32 + kb];
      bfrag[1][ks] = wt8[(size_t)(wv*32 + 16+ lr)*32 + kb];
    }
    #pragma unroll
    for (int ks=0; ks<4; ks++){
      int cb = (kh*4+ks)*64 + kg*16;
      int r0 = lr, r1 = 16+lr;
      s8v a0 = *(const s8v*)((const char*)s_ab + ((r0*512+cb) ^ ((r0&7)<<4)));
      s8v a1 = *(const s8v*)((const char*)s_ab + ((r1*512+cb) ^ ((r1&7)<<4)));
      acc00 = __builtin_amdgcn_mfma_f32_16x16x32_bf16(a0, bfrag[0][ks], acc00, 0,0,0);
      acc01 = __builtin_amdgcn_mfma_f32_16x16x32_bf16(a0, bfrag[1][ks], acc01, 0,0,0);
      acc10 = __builtin_amdgcn_mfma_f32_16x16x32_bf16(a1, bfrag[0][ks], acc10, 0,0,0);
      acc11 = __builtin_amdgcn_mfma_f32_16x16x32_bf16(a1, bfrag[1][ks], acc11, 0,0,0);
    }
  }
  __syncthreads();

  // ---- epilogue: acc -> LDS f32 [32][128]
  float* cbuf = (float*)s_ab;
  #pragma unroll
  for (int r=0;r<4;r++){
    int row0 = kg*4 + r;
    cbuf[(row0   )*DF + wv*32      + lr] = acc00[r];
    cbuf[(row0   )*DF + wv*32 + 16 + lr] = acc01[r];
    cbuf[(row0+16)*DF + wv*32      + lr] = acc10[r];
    cbuf[(row0+16)*DF + wv*32 + 16 + lr] = acc11[r];
  }
  __syncthreads();

  if (MODE==0){
    int row = t>>3, c0 = (t&7)*16;
    int node = node0+row;
    if (node<N){
      float x[16];
      #pragma unroll
      for (int j=0;j<16;j++) x[j] = fmaxf(cbuf[row*DF + c0 + j] + bias[c0+j], 0.f);
      unsigned f0 = __builtin_amdgcn_cvt_pk_fp8_f32(x[0], x[1], 0, false);
      f0 = __builtin_amdgcn_cvt_pk_fp8_f32(x[2], x[3], f0, true);
      unsigned f1 = __builtin_amdgcn_cvt_pk_fp8_f32(x[4], x[5], 0, false);
      f1 = __builtin_amdgcn_cvt_pk_fp8_f32(x[6], x[7], f1, true);
      unsigned f2 = __builtin_amdgcn_cvt_pk_fp8_f32(x[8], x[9], 0, false);
      f2 = __builtin_amdgcn_cvt_pk_fp8_f32(x[10], x[11], f2, true);
      unsigned f3 = __builtin_amdgcn_cvt_pk_fp8_f32(x[12], x[13], 0, false);
      f3 = __builtin_amdgcn_cvt_pk_fp8_f32(x[14], x[15], f3, true);
      *(uint4*)&h_out_f8[(size_t)node*DF + c0] = make_uint4(f0,f1,f2,f3);
    }
  } else {
    // fused pool: segment loop over sorted gid runs; one atomic per (segment,d)
    const int d = t&127, rh = t>>7;
    const float bd = bias[d];
    int segStart = 0;
    while (segStart < 32 && s_gid[segStart] >= 0){
      int g = s_gid[segStart];
      int segEnd = segStart+1;
      while (segEnd < 32 && s_gid[segEnd] == g) segEnd++;
      float p = 0.f;
      for (int r = segStart+rh; r < segEnd; r += 2)
        p += fmaxf(cbuf[r*DF + d] + bd, 0.f);
      if (rh==1) s_tmp[d] = p;
      __syncthreads();
      if (rh==0) atomicAdd(&gsum[g*DF+d], p + s_tmp[d]);
      __syncthreads();
      segStart = segEnd;
    }
  }
}

// ---------------- fused MLP head ----------------
__global__ __launch_bounds__(256)
void k_head(const float* __restrict__ gsum, const float* __restrict__ gcnt,
            const float* __restrict__ e1w, const float* __restrict__ e1b,
            const float* __restrict__ e2w, const float* __restrict__ e2b,
            const float* __restrict__ e3w, const float* __restrict__ e3b,
            const float* __restrict__ e4w, const float* __restrict__ e4b,
            const float* __restrict__ pw,  const float* __restrict__ pb,
            float* __restrict__ out, float* __restrict__ hidden){
  __shared__ float hg[DF];
  __shared__ float bufA[HID];
  __shared__ float bufB[HID];
  __shared__ float r0[HID], r1[HID];
  const int g = blockIdx.x, t = threadIdx.x;
  if (t<DF) hg[t] = gsum[g*DF+t] / fmaxf(gcnt[g],1.0f);
  __syncthreads();

  float acc = e1b[t];
  for (int k=0;k<DF;++k) acc += hg[k]*e1w[k*HID+t];
  float h1 = fmaxf(acc,0.f);
  hidden[g*HID+t] = h1;
  bufA[t] = h1;
  __syncthreads();

  acc = e2b[t];
  for (int k=0;k<HID;++k) acc += bufA[k]*e2w[k*HID+t];
  bufB[t] = fmaxf(acc,0.f);
  __syncthreads();

  acc = e3b[t];
  for (int k=0;k<HID;++k) acc += bufB[k]*e3w[k*HID+t];
  bufA[t] = fmaxf(acc,0.f);
  __syncthreads();

  acc = e4b[t];
  for (int k=0;k<HID;++k) acc += bufA[k]*e4w[k*HID+t];
  float h4 = fmaxf(acc,0.f);

  r0[t] = h4*pw[t*2+0];
  r1[t] = h4*pw[t*2+1];
  __syncthreads();
  for (int o=128;o>0;o>>=1){
    if (t<o){ r0[t]+=r0[t+o]; r1[t]+=r1[t+o]; }
    __syncthreads();
  }
  if (t==0){
    float y0 = r0[0]+pb[0], y1 = r1[0]+pb[1];
    float m = fmaxf(y0,y1);
    float l = m + logf(expf(y0-m)+expf(y1-m));
    out[g*2+0]=y0-l;
    out[g*2+1]=y1-l;
  }
}

extern "C" void kernel_launch(void* const* d_in, const int* in_sizes, int n_in,
                              void* d_out, int out_size, void* d_ws, size_t ws_size,
                              hipStream_t stream){
  const int* feat = (const int*)d_in[0];
  const int* src  = (const int*)d_in[1];
  const int* dst  = (const int*)d_in[2];
  const int* gid  = (const int*)d_in[3];
  const float* emb = (const float*)d_in[4];
  const float* ws0 = (const float*)d_in[5];
  const float* wn0 = (const float*)d_in[6];
  const float* b0  = (const float*)d_in[7];
  const float* ws1 = (const float*)d_in[8];
  const float* wn1 = (const float*)d_in[9];
  const float* b1  = (const float*)d_in[10];
  const float* e1w = (const float*)d_in[11];
  const float* e1b = (const float*)d_in[12];
  const float* e2w = (const float*)d_in[13];
  const float* e2b = (const float*)d_in[14];
  const float* e3w = (const float*)d_in[15];
  const float* e3b = (const float*)d_in[16];
  const float* e4w = (const float*)d_in[17];
  const float* e4b = (const float*)d_in[18];
  const float* pw  = (const float*)d_in[19];
  const float* pb  = (const float*)d_in[20];
  const int N = in_sizes[0];
  const int E = in_sizes[1];
  const int nvoc = in_sizes[4] / DF;

  char* basep = (char*)d_ws;
  size_t off=0;
  auto alloc=[&](size_t bytes)->void*{
    void* p = basep+off; off=(off+bytes+255)&~(size_t)255; return p;
  };
  unsigned char*  hA_f8 = (unsigned char*) alloc((size_t)N*DF);
  unsigned char*  hB_f8 = (unsigned char*) alloc((size_t)N*DF);
  unsigned char*  emb_f8= (unsigned char*) alloc((size_t)nvoc*DF);
  int*   offs  = (int*)  alloc((size_t)(N+1)*4);
  int*   csr   = (int*)  alloc((size_t)E*4);
  int*   gb    = (int*)  alloc(1024);
  int*   bcur  = (int*)  alloc(1024);
  unsigned short* wtb = (unsigned short*)alloc((size_t)2*DF*256*2);
  float* gsum  = (float*)alloc((size_t)NG*DF*4);
  float* gcnt  = (float*)alloc((size_t)NG*4);
  unsigned* pairs = (unsigned*)alloc((size_t)E*4);
  float* out    = (float*)d_out;
  float* hidden = out + NG*2;

  hipMemsetAsync(gb, 0, 1024, stream);
  hipMemsetAsync(bcur, 0, 1024, stream);
  hipMemsetAsync(gsum, 0, (size_t)NG*DF*4, stream);
  hipMemsetAsync(gcnt, 0, (size_t)NG*4, stream);

  const int NBK = (N+511)>>9;
  const int NC = (nvoc*(DF/8) + 255)/256;   // emb-convert blocks
  const int NP1 = (N*8 + 255)/256;          // gather blocks
  k_pre0<<<NC+768,256,0,stream>>>(emb,(unsigned*)emb_f8,nvoc,
                                  dst,gb,gid,gcnt,
                                  ws0,wn0,ws1,wn1,wtb,N,E,NC);
  k_mid<<<256+NP1,256,0,stream>>>(feat,(const unsigned*)emb_f8,
                                  (unsigned*)hA_f8,N,
                                  src,dst,gb,bcur,pairs,E);
  k_bcsr<<<NBK,256,0,stream>>>(pairs,gb,offs,csr,N,E);

  k_sage<0><<<(N+31)/32,256,0,stream>>>(hA_f8,offs,csr,wtb,        b0,
                                        hB_f8,nullptr,nullptr,N);
  k_sage<1><<<(N+31)/32,256,0,stream>>>(hB_f8,offs,csr,wtb+DF*256, b1,
                                        nullptr,gid,gsum,N);

  k_head<<<NG,HID,0,stream>>>(gsum,gcnt,e1w,e1b,e2w,e2b,e3w,e3b,e4w,e4b,
                              pw,pb,out,hidden);
}